// Round 1
// baseline (1005.172 us; speedup 1.0000x reference)
//
#include <hip/hip_runtime.h>
#include <hip/hip_bf16.h>

typedef __attribute__((ext_vector_type(4))) float  f32x4;
typedef __bf16 bf16x8 __attribute__((ext_vector_type(8)));
typedef __attribute__((ext_vector_type(4))) short  short4_t;

#define NWIN 1024
#define NQ   49
#define CDIM 512
#define NH   16

static __device__ __forceinline__ short f2bs(float f) {
    __hip_bfloat16 h = __float2bfloat16(f);
    return *reinterpret_cast<short*>(&h);
}

// ---------------------------------------------------------------------------
// Kernel 1: convert+transpose weights to bf16.  wqkvT[1536][512], wprojT[512][512]
// ---------------------------------------------------------------------------
__global__ __launch_bounds__(256) void k_prep_w(const float* __restrict__ qw,
                                                const float* __restrict__ kvw,
                                                const float* __restrict__ pw,
                                                short* __restrict__ wqkvT,
                                                short* __restrict__ wprojT) {
    int t = blockIdx.x * 256 + threadIdx.x;
    if (t < 1536 * 512) {
        int c = t >> 9, k = t & 511;
        float v = (c < 512) ? qw[k * 512 + c] : kvw[k * 1024 + (c - 512)];
        wqkvT[t] = f2bs(v);
    } else if (t < 1536 * 512 + 512 * 512) {
        int t2 = t - 1536 * 512;
        int c = t2 >> 9, k = t2 & 511;
        wprojT[t2] = f2bs(pw[k * 512 + c]);
    }
}

// ---------------------------------------------------------------------------
// Kernel 2: DynamicPosBias MLP + gather -> rpb[16][49][49] (fp32)
// ---------------------------------------------------------------------------
static __device__ __forceinline__ void ln_relu(const float* h, float* y,
                                               const float* __restrict__ g,
                                               const float* __restrict__ b) {
    float m = 0.f;
#pragma unroll
    for (int j = 0; j < 32; j++) m += h[j];
    m *= 0.03125f;
    float v = 0.f;
#pragma unroll
    for (int j = 0; j < 32; j++) { float d = h[j] - m; v += d * d; }
    v *= 0.03125f;
    float inv = rsqrtf(v + 1e-5f);
#pragma unroll
    for (int j = 0; j < 32; j++) y[j] = fmaxf((h[j] - m) * inv * g[j] + b[j], 0.f);
}

__global__ __launch_bounds__(256) void k_posbias(
    const float* __restrict__ ppw,  const float* __restrict__ ppb,
    const float* __restrict__ ln1g, const float* __restrict__ ln1b,
    const float* __restrict__ lin1w,const float* __restrict__ lin1b,
    const float* __restrict__ ln2g, const float* __restrict__ ln2b,
    const float* __restrict__ lin2w,const float* __restrict__ lin2b,
    const float* __restrict__ ln3g, const float* __restrict__ ln3b,
    const float* __restrict__ lin3w,const float* __restrict__ lin3b,
    float* __restrict__ rpb) {
    __shared__ float pf[169][16];
    int t = threadIdx.x;
    if (t < 169) {
        float h[32], y[32];
        float b0 = (float)(t / 13) - 6.0f;
        float b1 = (float)(t % 13) - 6.0f;
#pragma unroll
        for (int j = 0; j < 32; j++) h[j] = b0 * ppw[j] + b1 * ppw[32 + j] + ppb[j];
        // layer 1
        ln_relu(h, y, ln1g, ln1b);
#pragma unroll
        for (int j = 0; j < 32; j++) {
            float a = lin1b[j];
#pragma unroll
            for (int k = 0; k < 32; k++) a += y[k] * lin1w[k * 32 + j];
            h[j] = a;
        }
        // layer 2
        ln_relu(h, y, ln2g, ln2b);
#pragma unroll
        for (int j = 0; j < 32; j++) {
            float a = lin2b[j];
#pragma unroll
            for (int k = 0; k < 32; k++) a += y[k] * lin2w[k * 32 + j];
            h[j] = a;
        }
        // layer 3 (32 -> 16)
        ln_relu(h, y, ln3g, ln3b);
#pragma unroll
        for (int j = 0; j < 16; j++) {
            float a = lin3b[j];
#pragma unroll
            for (int k = 0; k < 32; k++) a += y[k] * lin3w[k * 16 + j];
            pf[t][j] = a;
        }
    }
    __syncthreads();
    for (int i = t; i < 16 * 49 * 49; i += 256) {
        int hh = i / 2401, rem = i % 2401, r = rem / 49, c = rem % 49;
        int ri = (r / 7 - c / 7 + 6) * 13 + (r % 7 - c % 7 + 6);
        rpb[i] = pf[ri][hh];
    }
}

// ---------------------------------------------------------------------------
// Kernel 3: fused qkv-GEMM + attention per window.
//  LDS: xs[49][512] bf16 swizzled (50176B) + sQK (16384B: q/k, aliased by P) +
//       vT[2][32][64] swizzled (8192B)  = 74752 B -> 2 blocks/CU
// ---------------------------------------------------------------------------
__global__ __launch_bounds__(256) void k_fused(const float* __restrict__ x,
                                               const short* __restrict__ wqkvT,
                                               const float* __restrict__ rpb,
                                               short* __restrict__ attnout) {
    __shared__ short xs[NQ * CDIM];   // [row][k], byte ^= (row&7)<<4
    __shared__ short sQK[8192];       // q: [hl*2048 + row*32 + d]; k: +4096; P aliases all
    __shared__ short vt[2 * 32 * 64]; // [hl][d][j], byte ^= (d&7)<<4

    const int b    = blockIdx.x;
    const int tid  = threadIdx.x;
    const int w    = tid >> 6;
    const int lane = tid & 63;
    const int l15  = lane & 15;
    const int lhi  = lane >> 4;

    // ---- stage x[b] (fp32) -> xs (bf16, swizzled)
    {
        const float* xb = x + (size_t)b * NQ * CDIM;
        for (int e = tid * 4; e < NQ * CDIM; e += 1024) {
            float4 v = *reinterpret_cast<const float4*>(xb + e);
            int row = e >> 9, k = e & 511;
            int byte = row * 1024 + ((k * 2) ^ ((row & 7) << 4));
            short4_t sv;
            sv.x = f2bs(v.x); sv.y = f2bs(v.y); sv.z = f2bs(v.z); sv.w = f2bs(v.w);
            *reinterpret_cast<short4_t*>(reinterpret_cast<char*>(xs) + byte) = sv;
        }
    }
    __syncthreads();

    const int hl   = w >> 1;   // head-local within pair (phases B/C)
    const int msub = w & 1;

    // A-fragment row bases (row clamped to 48; rows>=49 produce garbage that is masked later)
    int rowbase[4], srow[4];
#pragma unroll
    for (int m = 0; m < 4; m++) {
        int ar = m * 16 + l15; if (ar > 48) ar = 48;
        rowbase[m] = ar * 1024;
        srow[m]    = (ar & 7) << 4;
    }

    for (int g = 0; g < 8; g++) {
        const int head = 2 * g + hl;
        // ================= Phase A: qkv GEMM for heads 2g, 2g+1 ==============
        f32x4 acc[4][3];
#pragma unroll
        for (int m = 0; m < 4; m++)
#pragma unroll
            for (int j = 0; j < 3; j++) acc[m][j] = (f32x4){0.f, 0.f, 0.f, 0.f};

        const short* bptr[3];
#pragma unroll
        for (int j = 0; j < 3; j++) {
            int t4 = 3 * w + j;            // ntile 0..11
            int sec = t4 >> 2, tt = t4 & 3;
            int row = sec * 512 + (2 * g + (tt >> 1)) * 32 + (tt & 1) * 16 + l15;
            bptr[j] = wqkvT + row * 512 + lhi * 8;
        }
#pragma unroll
        for (int ks = 0; ks < 16; ks++) {
            bf16x8 bf[3];
#pragma unroll
            for (int j = 0; j < 3; j++)
                bf[j] = *reinterpret_cast<const bf16x8*>(bptr[j] + ks * 32);
            int kbyte = ks * 64 + lhi * 16;
#pragma unroll
            for (int m = 0; m < 4; m++) {
                bf16x8 af = *reinterpret_cast<const bf16x8*>(
                    reinterpret_cast<const char*>(xs) + rowbase[m] + (kbyte ^ srow[m]));
#pragma unroll
                for (int j = 0; j < 3; j++)
                    acc[m][j] = __builtin_amdgcn_mfma_f32_16x16x32_bf16(af, bf[j], acc[m][j], 0, 0, 0);
            }
        }
        // epilogue: scatter to q / k / vT (bf16 in LDS)
#pragma unroll
        for (int j = 0; j < 3; j++) {
            int t4 = 3 * w + j;
            int sec = t4 >> 2, tt = t4 & 3;
            int hle = tt >> 1;
            int d   = (tt & 1) * 16 + l15;
#pragma unroll
            for (int m = 0; m < 4; m++) {
#pragma unroll
                for (int i = 0; i < 4; i++) {
                    int row = m * 16 + lhi * 4 + i;
                    short val = f2bs(acc[m][j][i]);
                    if (sec == 0)      sQK[hle * 2048 + row * 32 + d] = val;
                    else if (sec == 1) sQK[4096 + hle * 2048 + row * 32 + d] = val;
                    else {
                        int byte = d * 128 + ((row * 2) ^ ((d & 7) << 4));
                        *reinterpret_cast<short*>(reinterpret_cast<char*>(vt) + hle * 4096 + byte) = val;
                    }
                }
            }
        }
        __syncthreads();

        // ================= Phase B: scores + softmax (in-register) ===========
        const short* qsb = sQK + hl * 2048;
        const short* ksb = sQK + 4096 + hl * 2048;
        bf16x8 kb[4];
#pragma unroll
        for (int nt = 0; nt < 4; nt++) {
            int j = nt * 16 + l15;
            kb[nt] = *reinterpret_cast<const bf16x8*>(ksb + j * 32 + lhi * 8);
        }
        f32x4 sc[2][4];
#pragma unroll
        for (int mt = 0; mt < 2; mt++) {
            int r = (msub * 2 + mt) * 16 + l15;
            bf16x8 qa = *reinterpret_cast<const bf16x8*>(qsb + r * 32 + lhi * 8);
#pragma unroll
            for (int nt = 0; nt < 4; nt++) {
                f32x4 z = (f32x4){0.f, 0.f, 0.f, 0.f};
                sc[mt][nt] = __builtin_amdgcn_mfma_f32_16x16x32_bf16(qa, kb[nt], z, 0, 0, 0);
            }
        }
        const float scale = 0.17677669529663687f; // 32^-0.5
        float p[2][4][4];
#pragma unroll
        for (int mt = 0; mt < 2; mt++) {
#pragma unroll
            for (int i = 0; i < 4; i++) {
                int r  = (msub * 2 + mt) * 16 + lhi * 4 + i;
                int rr = r > 48 ? 48 : r;
                const float* rp = rpb + head * 2401 + rr * 49;
                float vv[4];
#pragma unroll
                for (int nt = 0; nt < 4; nt++) {
                    int c = nt * 16 + l15;
                    vv[nt] = (c < 49) ? (sc[mt][nt][i] * scale + rp[c]) : -3.0e38f;
                }
                float mx = fmaxf(fmaxf(vv[0], vv[1]), fmaxf(vv[2], vv[3]));
#pragma unroll
                for (int dd = 1; dd < 16; dd <<= 1) mx = fmaxf(mx, __shfl_xor(mx, dd, 64));
                float s0 = 0.f;
#pragma unroll
                for (int nt = 0; nt < 4; nt++) { vv[nt] = __expf(vv[nt] - mx); s0 += vv[nt]; }
#pragma unroll
                for (int dd = 1; dd < 16; dd <<= 1) s0 += __shfl_xor(s0, dd, 64);
                float rs = 1.0f / s0;
#pragma unroll
                for (int nt = 0; nt < 4; nt++) p[mt][nt][i] = vv[nt] * rs;
            }
        }
        __syncthreads();  // all q/k reads done -> safe to overwrite via alias
        // write P (bf16) into alias region: ps_hl = sQK + hl*4096, [64][64] swizzled
        {
            short* psb = sQK + hl * 4096;
#pragma unroll
            for (int mt = 0; mt < 2; mt++)
#pragma unroll
                for (int i = 0; i < 4; i++) {
                    int r = (msub * 2 + mt) * 16 + lhi * 4 + i;
#pragma unroll
                    for (int nt = 0; nt < 4; nt++) {
                        int c = nt * 16 + l15;
                        int byte = r * 128 + ((c * 2) ^ ((r & 7) << 4));
                        *reinterpret_cast<short*>(reinterpret_cast<char*>(psb) + byte) = f2bs(p[mt][nt][i]);
                    }
                }
        }
        __syncthreads();

        // ================= Phase C: PV ======================================
        f32x4 ov[2][2];
#pragma unroll
        for (int mt = 0; mt < 2; mt++)
#pragma unroll
            for (int nt = 0; nt < 2; nt++) ov[mt][nt] = (f32x4){0.f, 0.f, 0.f, 0.f};
        const char* psc = reinterpret_cast<const char*>(sQK + hl * 4096);
        const char* vtc = reinterpret_cast<const char*>(vt) + hl * 4096;
#pragma unroll
        for (int ks2 = 0; ks2 < 2; ks2++) {
            int j0b = ks2 * 64 + lhi * 16;
            bf16x8 pa[2], vb[2];
#pragma unroll
            for (int mt = 0; mt < 2; mt++) {
                int r = (msub * 2 + mt) * 16 + l15;
                pa[mt] = *reinterpret_cast<const bf16x8*>(psc + r * 128 + (j0b ^ ((r & 7) << 4)));
            }
#pragma unroll
            for (int nt = 0; nt < 2; nt++) {
                int d = nt * 16 + l15;
                vb[nt] = *reinterpret_cast<const bf16x8*>(vtc + d * 128 + (j0b ^ ((d & 7) << 4)));
            }
#pragma unroll
            for (int mt = 0; mt < 2; mt++)
#pragma unroll
                for (int nt = 0; nt < 2; nt++)
                    ov[mt][nt] = __builtin_amdgcn_mfma_f32_16x16x32_bf16(pa[mt], vb[nt], ov[mt][nt], 0, 0, 0);
        }
        // epilogue -> attnout (bf16, [b*49+r][head*32+d])
#pragma unroll
        for (int mt = 0; mt < 2; mt++)
#pragma unroll
            for (int nt = 0; nt < 2; nt++)
#pragma unroll
                for (int i = 0; i < 4; i++) {
                    int r = (msub * 2 + mt) * 16 + lhi * 4 + i;
                    if (r < 49) {
                        int col = head * 32 + nt * 16 + l15;
                        attnout[((size_t)b * 49 + r) * 512 + col] = f2bs(ov[mt][nt][i]);
                    }
                }
        __syncthreads();
    }
}

// ---------------------------------------------------------------------------
// Kernel 4: output projection.  out[b*49+r][c] = attnout[b] @ wprojT + proj_b
// ---------------------------------------------------------------------------
__global__ __launch_bounds__(256) void k_proj(const short* __restrict__ attnout,
                                              const short* __restrict__ wprojT,
                                              const float* __restrict__ projb,
                                              float* __restrict__ out) {
    const int b    = blockIdx.x;
    const int tid  = threadIdx.x;
    const int w    = tid >> 6;
    const int lane = tid & 63;
    const int l15  = lane & 15;
    const int lhi  = lane >> 4;
    const short* ab = attnout + (size_t)b * 49 * 512;

    int arow[4];
#pragma unroll
    for (int m = 0; m < 4; m++) {
        int r = m * 16 + l15; if (r > 48) r = 48;
        arow[m] = r * 512;
    }
#pragma unroll
    for (int pass = 0; pass < 2; pass++) {
        int colbase = w * 128 + pass * 64;
        f32x4 cacc[4][4];
#pragma unroll
        for (int m = 0; m < 4; m++)
#pragma unroll
            for (int j = 0; j < 4; j++) cacc[m][j] = (f32x4){0.f, 0.f, 0.f, 0.f};
        const short* bcol[4];
#pragma unroll
        for (int j = 0; j < 4; j++)
            bcol[j] = wprojT + (colbase + j * 16 + l15) * 512 + lhi * 8;
#pragma unroll
        for (int ks = 0; ks < 16; ks++) {
            bf16x8 bf[4];
#pragma unroll
            for (int j = 0; j < 4; j++)
                bf[j] = *reinterpret_cast<const bf16x8*>(bcol[j] + ks * 32);
#pragma unroll
            for (int m = 0; m < 4; m++) {
                bf16x8 af = *reinterpret_cast<const bf16x8*>(ab + arow[m] + lhi * 8 + ks * 32);
#pragma unroll
                for (int j = 0; j < 4; j++)
                    cacc[m][j] = __builtin_amdgcn_mfma_f32_16x16x32_bf16(af, bf[j], cacc[m][j], 0, 0, 0);
            }
        }
#pragma unroll
        for (int j = 0; j < 4; j++) {
            int col = colbase + j * 16 + l15;
            float pbv = projb[col];
#pragma unroll
            for (int m = 0; m < 4; m++)
#pragma unroll
                for (int i = 0; i < 4; i++) {
                    int r = m * 16 + lhi * 4 + i;
                    if (r < 49)
                        out[((size_t)b * 49 + r) * 512 + col] = cacc[m][j][i] + pbv;
                }
        }
    }
}

// ---------------------------------------------------------------------------
extern "C" void kernel_launch(void* const* d_in, const int* in_sizes, int n_in,
                              void* d_out, int out_size, void* d_ws, size_t ws_size,
                              hipStream_t stream) {
    const float* x    = (const float*)d_in[0];
    const float* qw   = (const float*)d_in[1];
    const float* kvw  = (const float*)d_in[2];
    const float* pw   = (const float*)d_in[3];
    const float* pb   = (const float*)d_in[4];
    const float* ppw  = (const float*)d_in[5];
    const float* ppb  = (const float*)d_in[6];
    const float* ln1g = (const float*)d_in[7];
    const float* ln1b = (const float*)d_in[8];
    const float* lin1w= (const float*)d_in[9];
    const float* lin1b= (const float*)d_in[10];
    const float* ln2g = (const float*)d_in[11];
    const float* ln2b = (const float*)d_in[12];
    const float* lin2w= (const float*)d_in[13];
    const float* lin2b= (const float*)d_in[14];
    const float* ln3g = (const float*)d_in[15];
    const float* ln3b = (const float*)d_in[16];
    const float* lin3w= (const float*)d_in[17];
    const float* lin3b= (const float*)d_in[18];
    float* out = (float*)d_out;

    char* ws = (char*)d_ws;
    short* wqkvT   = (short*)(ws);                 // 1,572,864 B
    short* wprojT  = (short*)(ws + 1572864);       //   524,288 B
    float* rpb     = (float*)(ws + 2097152);       //   153,664 B
    short* attnout = (short*)(ws + 2252800);       // 51,380,224 B  (total ~53.6 MB)

    k_prep_w<<<4096, 256, 0, stream>>>(qw, kvw, pw, wqkvT, wprojT);
    k_posbias<<<1, 256, 0, stream>>>(ppw, ppb, ln1g, ln1b, lin1w, lin1b,
                                     ln2g, ln2b, lin2w, lin2b,
                                     ln3g, ln3b, lin3w, lin3b, rpb);
    k_fused<<<NWIN, 256, 0, stream>>>(x, wqkvT, rpb, attnout);
    k_proj<<<NWIN, 256, 0, stream>>>(attnout, wprojT, pb, out);
}

// Round 6
// 738.495 us; speedup vs baseline: 1.3611x; 1.3611x over previous
//
#include <hip/hip_runtime.h>
#include <hip/hip_bf16.h>

typedef __attribute__((ext_vector_type(4))) float  f32x4;
typedef __bf16 bf16x8 __attribute__((ext_vector_type(8)));
typedef __attribute__((ext_vector_type(8))) short  short8_t;

#define NWIN_CHUNK 256                 // windows per chunk (4 chunks of 256)
#define MCH (NWIN_CHUNK * 49)          // 12544 = 98*128 rows per chunk

static __device__ __forceinline__ short f2bs(float f) {
    __hip_bfloat16 h = __float2bfloat16(f);
    return *reinterpret_cast<short*>(&h);
}

static __device__ __forceinline__ void gload_lds16(const void* g, void* l) {
    __builtin_amdgcn_global_load_lds(
        (const __attribute__((address_space(1))) void*)g,
        (__attribute__((address_space(3))) void*)l, 16, 0, 0);
}

// ---------------------------------------------------------------------------
// weights -> bf16 transposed.  wqkvT[1536][512], wprojT[512][512]
// ---------------------------------------------------------------------------
__global__ __launch_bounds__(256) void k_prep_w(const float* __restrict__ qw,
                                                const float* __restrict__ kvw,
                                                const float* __restrict__ pw,
                                                short* __restrict__ wqkvT,
                                                short* __restrict__ wprojT) {
    int t = blockIdx.x * 256 + threadIdx.x;
    if (t < 1536 * 512) {
        int c = t >> 9, k = t & 511;
        float v = (c < 512) ? qw[k * 512 + c] : kvw[k * 1024 + (c - 512)];
        wqkvT[t] = f2bs(v);
    } else {
        int t2 = t - 1536 * 512;
        int c = t2 >> 9, k = t2 & 511;
        wprojT[t2] = f2bs(pw[k * 512 + c]);
    }
}

// ---------------------------------------------------------------------------
// x chunk (fp32) -> xb (bf16)
// ---------------------------------------------------------------------------
__global__ __launch_bounds__(256) void k_prep_x(const float* __restrict__ x,
                                                short* __restrict__ xb) {
    size_t i = ((size_t)blockIdx.x * 256 + threadIdx.x) * 8;
    float4 a = *reinterpret_cast<const float4*>(x + i);
    float4 c = *reinterpret_cast<const float4*>(x + i + 4);
    short8_t s;
    s[0] = f2bs(a.x); s[1] = f2bs(a.y); s[2] = f2bs(a.z); s[3] = f2bs(a.w);
    s[4] = f2bs(c.x); s[5] = f2bs(c.y); s[6] = f2bs(c.z); s[7] = f2bs(c.w);
    *reinterpret_cast<short8_t*>(xb + i) = s;
}

// ---------------------------------------------------------------------------
// DynamicPosBias MLP + gather -> rpb[16][49][49] (fp32)
// ---------------------------------------------------------------------------
static __device__ __forceinline__ void ln_relu(const float* h, float* y,
                                               const float* __restrict__ g,
                                               const float* __restrict__ b) {
    float m = 0.f;
#pragma unroll
    for (int j = 0; j < 32; j++) m += h[j];
    m *= 0.03125f;
    float v = 0.f;
#pragma unroll
    for (int j = 0; j < 32; j++) { float d = h[j] - m; v += d * d; }
    v *= 0.03125f;
    float inv = rsqrtf(v + 1e-5f);
#pragma unroll
    for (int j = 0; j < 32; j++) y[j] = fmaxf((h[j] - m) * inv * g[j] + b[j], 0.f);
}

__global__ __launch_bounds__(256) void k_posbias(
    const float* __restrict__ ppw,  const float* __restrict__ ppb,
    const float* __restrict__ ln1g, const float* __restrict__ ln1b,
    const float* __restrict__ lin1w,const float* __restrict__ lin1b,
    const float* __restrict__ ln2g, const float* __restrict__ ln2b,
    const float* __restrict__ lin2w,const float* __restrict__ lin2b,
    const float* __restrict__ ln3g, const float* __restrict__ ln3b,
    const float* __restrict__ lin3w,const float* __restrict__ lin3b,
    float* __restrict__ rpb) {
    __shared__ float pf[169][16];
    int t = threadIdx.x;
    if (t < 169) {
        float h[32], y[32];
        float b0 = (float)(t / 13) - 6.0f;
        float b1 = (float)(t % 13) - 6.0f;
#pragma unroll
        for (int j = 0; j < 32; j++) h[j] = b0 * ppw[j] + b1 * ppw[32 + j] + ppb[j];
        ln_relu(h, y, ln1g, ln1b);
#pragma unroll
        for (int j = 0; j < 32; j++) {
            float a = lin1b[j];
#pragma unroll
            for (int k = 0; k < 32; k++) a += y[k] * lin1w[k * 32 + j];
            h[j] = a;
        }
        ln_relu(h, y, ln2g, ln2b);
#pragma unroll
        for (int j = 0; j < 32; j++) {
            float a = lin2b[j];
#pragma unroll
            for (int k = 0; k < 32; k++) a += y[k] * lin2w[k * 32 + j];
            h[j] = a;
        }
        ln_relu(h, y, ln3g, ln3b);
#pragma unroll
        for (int j = 0; j < 16; j++) {
            float a = lin3b[j];
#pragma unroll
            for (int k = 0; k < 32; k++) a += y[k] * lin3w[k * 16 + j];
            pf[t][j] = a;
        }
    }
    __syncthreads();
    for (int i = t; i < 16 * 49 * 49; i += 256) {
        int hh = i / 2401, rem = i % 2401, r = rem / 49, c = rem % 49;
        int ri = (r / 7 - c / 7 + 6) * 13 + (r % 7 - c % 7 + 6);
        rpb[i] = pf[ri][hh];
    }
}

// ---------------------------------------------------------------------------
// m97-style GEMM: C[M][NT*128] = A[M][512] * B^T   (B stored [col][k])
//  128x128 tile, BK=64, 4 waves (2x2 of 64x64), global_load_lds width 16.
//  grid = (M/128)*NT, must be divisible by 8 (XCD swizzle).
// ---------------------------------------------------------------------------
template<int NT, int ASTR, bool OUTF32>
__global__ __launch_bounds__(256) void k_gemm(const short* __restrict__ A,
                                              const short* __restrict__ Bw,
                                              const float* __restrict__ bias,
                                              short* __restrict__ Cbf,
                                              float* __restrict__ Cf) {
    __shared__ short As[128 * 64];
    __shared__ short Bs[128 * 64];
    const int cpx = gridDim.x >> 3;
    int wg = (blockIdx.x & 7) * cpx + (blockIdx.x >> 3);  // XCD-contiguous
    const int mt = wg / NT, nt = wg % NT;
    const int brow = mt * 128, bcol = nt * 128;
    const int tid = threadIdx.x, w = tid >> 6, lane = tid & 63;
    const int l15 = lane & 15, lhi = lane >> 4;
    const int wr = w >> 1, wc = w & 1;

    const short* Ap = A + (size_t)(brow + (tid >> 3)) * ASTR + (tid & 7) * 8;
    const short* Bp = Bw + (size_t)(bcol + (tid >> 3)) * 512 + (tid & 7) * 8;
    short* asd = As + w * 512;
    short* bsd = Bs + w * 512;

    f32x4 acc[4][4];
#pragma unroll
    for (int m = 0; m < 4; m++)
#pragma unroll
        for (int n = 0; n < 4; n++) acc[m][n] = (f32x4){0.f, 0.f, 0.f, 0.f};

    for (int kt = 0; kt < 8; ++kt) {
        if (kt) __syncthreads();
#pragma unroll
        for (int p = 0; p < 4; ++p) {
            gload_lds16(Ap + (size_t)kt * 64 + (size_t)p * 32 * ASTR, asd + p * 2048);
            gload_lds16(Bp + (size_t)kt * 64 + (size_t)p * 32 * 512,  bsd + p * 2048);
        }
        __syncthreads();
#pragma unroll
        for (int ks = 0; ks < 2; ++ks) {
            bf16x8 af[4], bf[4];
#pragma unroll
            for (int m = 0; m < 4; ++m)
                af[m] = *reinterpret_cast<const bf16x8*>(As + (wr * 64 + m * 16 + l15) * 64 + ks * 32 + lhi * 8);
#pragma unroll
            for (int n = 0; n < 4; ++n)
                bf[n] = *reinterpret_cast<const bf16x8*>(Bs + (wc * 64 + n * 16 + l15) * 64 + ks * 32 + lhi * 8);
#pragma unroll
            for (int m = 0; m < 4; ++m)
#pragma unroll
                for (int n = 0; n < 4; ++n)
                    acc[m][n] = __builtin_amdgcn_mfma_f32_16x16x32_bf16(af[m], bf[n], acc[m][n], 0, 0, 0);
        }
    }
#pragma unroll
    for (int n = 0; n < 4; ++n) {
        int col = bcol + wc * 64 + n * 16 + l15;
        if constexpr (OUTF32) {
            float pb = bias[col];
#pragma unroll
            for (int m = 0; m < 4; ++m)
#pragma unroll
                for (int i = 0; i < 4; ++i) {
                    int row = brow + wr * 64 + m * 16 + lhi * 4 + i;
                    Cf[(size_t)row * (NT * 128) + col] = acc[m][n][i] + pb;
                }
        } else {
#pragma unroll
            for (int m = 0; m < 4; ++m)
#pragma unroll
                for (int i = 0; i < 4; ++i) {
                    int row = brow + wr * 64 + m * 16 + lhi * 4 + i;
                    Cbf[(size_t)row * (NT * 128) + col] = f2bs(acc[m][n][i]);
                }
        }
    }
}

// ---------------------------------------------------------------------------
// Attention: grid = NWIN_CHUNK*4 blocks; 4 waves/block; 1 head per wave.
// q,k frags global->reg; V transposed into per-wave swizzled LDS; P via
// per-wave swizzled LDS.  O overwrites the q-region (cols head*32..+31).
// No __syncthreads needed (all LDS per-wave private).
// ---------------------------------------------------------------------------
__global__ __launch_bounds__(256) void k_attn(short* __restrict__ qkv,
                                              const float* __restrict__ rpbt) {
    __shared__ short Pl[4][4096];   // per-wave 64x64 bf16, byte ^= (r&7)<<4
    __shared__ short Vt[4][2048];   // per-wave 32x64 bf16 (vT), byte ^= (d&7)<<4
    const int bid = blockIdx.x;
    const int wid = (bid & 7) * 128 + (bid >> 3);   // XCD-contiguous (grid 1024)
    const int cw = wid >> 2, qg = wid & 3;
    const int tid = threadIdx.x, w = tid >> 6, lane = tid & 63;
    const int l15 = lane & 15, lhi = lane >> 4;
    const int head = qg * 4 + w;
    char* Pw  = reinterpret_cast<char*>(Pl[w]);
    char* vtw = reinterpret_cast<char*>(Vt[w]);

    // zero vT pad columns (c=49..63)
    for (int t = lane; t < 480; t += 64) {
        int c = 49 + (t >> 5), d = t & 31;
        *reinterpret_cast<short*>(vtw + d * 128 + ((c * 2) ^ ((d & 7) << 4))) = 0;
    }
    short* qb = qkv + (size_t)cw * 49 * 1536 + head * 32;
    const float scale = 0.17677669529663687f;   // 32^-0.5

    // K fragments (B-operand of QK^T): lane group l15 = key row c
    bf16x8 kf[4];
#pragma unroll
    for (int n = 0; n < 4; ++n) {
        int c = n * 16 + l15; if (c > 48) c = 48;
        kf[n] = *reinterpret_cast<const bf16x8*>(qb + 512 + (size_t)c * 1536 + lhi * 8);
    }
    // stage V transposed into LDS
    if (lane < 49) {
        const short* vrow = qb + 1024 + (size_t)lane * 1536;
#pragma unroll
        for (int dv = 0; dv < 4; ++dv) {
            short8_t vv = *reinterpret_cast<const short8_t*>(vrow + dv * 8);
#pragma unroll
            for (int e = 0; e < 8; ++e) {
                int d = dv * 8 + e;
                *reinterpret_cast<short*>(vtw + d * 128 + ((lane * 2) ^ ((d & 7) << 4))) = vv[e];
            }
        }
    }
    // QK^T + softmax + P write
#pragma unroll
    for (int m = 0; m < 4; ++m) {
        int r = m * 16 + l15; if (r > 48) r = 48;
        bf16x8 qf = *reinterpret_cast<const bf16x8*>(qb + (size_t)r * 1536 + lhi * 8);
        f32x4 sc[4];
#pragma unroll
        for (int n = 0; n < 4; ++n) {
            f32x4 z = (f32x4){0.f, 0.f, 0.f, 0.f};
            sc[n] = __builtin_amdgcn_mfma_f32_16x16x32_bf16(qf, kf[n], z, 0, 0, 0);
        }
#pragma unroll
        for (int i = 0; i < 4; ++i) {
            int rr = m * 16 + lhi * 4 + i;
            int rc = rr > 48 ? 48 : rr;
            const float* rp = rpbt + head * 2401 + rc * 49;
            float vv[4];
#pragma unroll
            for (int n = 0; n < 4; ++n) {
                int c = n * 16 + l15;
                vv[n] = (c < 49) ? sc[n][i] * scale + rp[c] : -3.0e38f;
            }
            float mx = fmaxf(fmaxf(vv[0], vv[1]), fmaxf(vv[2], vv[3]));
#pragma unroll
            for (int d = 1; d < 16; d <<= 1) mx = fmaxf(mx, __shfl_xor(mx, d, 64));
            float s0 = 0.f;
#pragma unroll
            for (int n = 0; n < 4; ++n) { vv[n] = __expf(vv[n] - mx); s0 += vv[n]; }
#pragma unroll
            for (int d = 1; d < 16; d <<= 1) s0 += __shfl_xor(s0, d, 64);
            float rs = 1.0f / s0;
#pragma unroll
            for (int n = 0; n < 4; ++n) {
                int c = n * 16 + l15;
                *reinterpret_cast<short*>(Pw + rr * 128 + ((c * 2) ^ ((rr & 7) << 4))) = f2bs(vv[n] * rs);
            }
        }
    }
    // PV
    f32x4 ov[4][2];
#pragma unroll
    for (int m = 0; m < 4; ++m)
#pragma unroll
        for (int n = 0; n < 2; ++n) ov[m][n] = (f32x4){0.f, 0.f, 0.f, 0.f};
#pragma unroll
    for (int ks = 0; ks < 2; ++ks) {
        int cb = ks * 64 + lhi * 16;
        bf16x8 pa[4], vb[2];
#pragma unroll
        for (int m = 0; m < 4; ++m) {
            int r = m * 16 + l15;
            pa[m] = *reinterpret_cast<const bf16x8*>(Pw + r * 128 + (cb ^ ((r & 7) << 4)));
        }
#pragma unroll
        for (int n = 0; n < 2; ++n) {
            int d = n * 16 + l15;
            vb[n] = *reinterpret_cast<const bf16x8*>(vtw + d * 128 + (cb ^ ((d & 7) << 4)));
        }
#pragma unroll
        for (int m = 0; m < 4; ++m)
#pragma unroll
            for (int n = 0; n < 2; ++n)
                ov[m][n] = __builtin_amdgcn_mfma_f32_16x16x32_bf16(pa[m], vb[n], ov[m][n], 0, 0, 0);
    }
    // write O into the (fully consumed) q-region of this head
#pragma unroll
    for (int m = 0; m < 4; ++m)
#pragma unroll
        for (int n = 0; n < 2; ++n)
#pragma unroll
            for (int i = 0; i < 4; ++i) {
                int rr = m * 16 + lhi * 4 + i;
                if (rr < 49) qb[(size_t)rr * 1536 + n * 16 + l15] = f2bs(ov[m][n][i]);
            }
}

// ---------------------------------------------------------------------------
extern "C" void kernel_launch(void* const* d_in, const int* in_sizes, int n_in,
                              void* d_out, int out_size, void* d_ws, size_t ws_size,
                              hipStream_t stream) {
    const float* x    = (const float*)d_in[0];
    const float* qw   = (const float*)d_in[1];
    const float* kvw  = (const float*)d_in[2];
    const float* pw   = (const float*)d_in[3];
    const float* pb   = (const float*)d_in[4];
    const float* ppw  = (const float*)d_in[5];
    const float* ppb  = (const float*)d_in[6];
    const float* ln1g = (const float*)d_in[7];
    const float* ln1b = (const float*)d_in[8];
    const float* lin1w= (const float*)d_in[9];
    const float* lin1b= (const float*)d_in[10];
    const float* ln2g = (const float*)d_in[11];
    const float* ln2b = (const float*)d_in[12];
    const float* lin2w= (const float*)d_in[13];
    const float* lin2b= (const float*)d_in[14];
    const float* ln3g = (const float*)d_in[15];
    const float* ln3b = (const float*)d_in[16];
    const float* lin3w= (const float*)d_in[17];
    const float* lin3b= (const float*)d_in[18];
    float* out = (float*)d_out;

    // workspace layout — total 53,633,024 B (== round-1 proven footprint)
    char* ws = (char*)d_ws;
    short* wqkvT  = (short*)(ws);                  //  1,572,864 B
    short* wprojT = (short*)(ws + 1572864);        //    524,288 B
    float* rpb    = (float*)(ws + 2097152);        //    153,664 B (+pad)
    short* xbc    = (short*)(ws + 2252800);        // 12,845,056 B (chunk)
    short* qkvc   = (short*)(ws + 15097856);       // 38,535,168 B (chunk)

    k_prep_w<<<4096, 256, 0, stream>>>(qw, kvw, pw, wqkvT, wprojT);
    k_posbias<<<1, 256, 0, stream>>>(ppw, ppb, ln1g, ln1b, lin1w, lin1b,
                                     ln2g, ln2b, lin2w, lin2b,
                                     ln3g, ln3b, lin3w, lin3b, rpb);
    for (int c = 0; c < 4; ++c) {
        const float* xc = x + (size_t)c * MCH * 512;
        float* outc = out + (size_t)c * MCH * 512;
        k_prep_x<<<3136, 256, 0, stream>>>(xc, xbc);
        k_gemm<12, 512, false><<<1176, 256, 0, stream>>>(xbc, wqkvT, nullptr, qkvc, nullptr);
        k_attn<<<1024, 256, 0, stream>>>(qkvc, rpb);
        k_gemm<4, 1536, true><<<392, 256, 0, stream>>>(qkvc, wprojT, pb, nullptr, outc);
    }
}

// Round 7
// 521.440 us; speedup vs baseline: 1.9277x; 1.4163x over previous
//
#include <hip/hip_runtime.h>
#include <hip/hip_bf16.h>

typedef __attribute__((ext_vector_type(4))) float  f32x4;
typedef __bf16 bf16x8 __attribute__((ext_vector_type(8)));
typedef __attribute__((ext_vector_type(8))) short  short8_t;

#define NWIN_CHUNK 256                 // windows per chunk (4 chunks of 256)
#define MCH (NWIN_CHUNK * 49)          // 12544 = 98*128 rows per chunk

static __device__ __forceinline__ short f2bs(float f) {
    __hip_bfloat16 h = __float2bfloat16(f);
    return *reinterpret_cast<short*>(&h);
}

static __device__ __forceinline__ void gload_lds16(const void* g, void* l) {
    __builtin_amdgcn_global_load_lds(
        (const __attribute__((address_space(1))) void*)g,
        (__attribute__((address_space(3))) void*)l, 16, 0, 0);
}

// ---------------------------------------------------------------------------
// weights -> bf16 transposed.  wqkvT[1536][512], wprojT[512][512]
// ---------------------------------------------------------------------------
__global__ __launch_bounds__(256) void k_prep_w(const float* __restrict__ qw,
                                                const float* __restrict__ kvw,
                                                const float* __restrict__ pw,
                                                short* __restrict__ wqkvT,
                                                short* __restrict__ wprojT) {
    int t = blockIdx.x * 256 + threadIdx.x;
    if (t < 1536 * 512) {
        int c = t >> 9, k = t & 511;
        float v = (c < 512) ? qw[k * 512 + c] : kvw[k * 1024 + (c - 512)];
        wqkvT[t] = f2bs(v);
    } else {
        int t2 = t - 1536 * 512;
        int c = t2 >> 9, k = t2 & 511;
        wprojT[t2] = f2bs(pw[k * 512 + c]);
    }
}

// ---------------------------------------------------------------------------
// x chunk (fp32) -> xb (bf16)
// ---------------------------------------------------------------------------
__global__ __launch_bounds__(256) void k_prep_x(const float* __restrict__ x,
                                                short* __restrict__ xb) {
    size_t i = ((size_t)blockIdx.x * 256 + threadIdx.x) * 8;
    float4 a = *reinterpret_cast<const float4*>(x + i);
    float4 c = *reinterpret_cast<const float4*>(x + i + 4);
    short8_t s;
    s[0] = f2bs(a.x); s[1] = f2bs(a.y); s[2] = f2bs(a.z); s[3] = f2bs(a.w);
    s[4] = f2bs(c.x); s[5] = f2bs(c.y); s[6] = f2bs(c.z); s[7] = f2bs(c.w);
    *reinterpret_cast<short8_t*>(xb + i) = s;
}

// ---------------------------------------------------------------------------
// DynamicPosBias MLP: 169 blocks x 64 threads (1 wave).  Row t = blockIdx.x,
// lane j = output channel.  Weights staged in LDS; LN via shfl butterfly;
// inter-layer y vector via LDS.  Writes pf[169][16].
// ---------------------------------------------------------------------------
static __device__ __forceinline__ float ln_relu_lane(float h, float g, float b) {
    float m = h;
#pragma unroll
    for (int d = 1; d < 32; d <<= 1) m += __shfl_xor(m, d, 64);
    m *= 0.03125f;
    float dv = h - m;
    float v = dv * dv;
#pragma unroll
    for (int d = 1; d < 32; d <<= 1) v += __shfl_xor(v, d, 64);
    v *= 0.03125f;
    return fmaxf(dv * rsqrtf(v + 1e-5f) * g + b, 0.f);
}

__global__ __launch_bounds__(64) void k_pos_mlp(
    const float* __restrict__ ppw,  const float* __restrict__ ppb,
    const float* __restrict__ ln1g, const float* __restrict__ ln1b,
    const float* __restrict__ lin1w,const float* __restrict__ lin1b,
    const float* __restrict__ ln2g, const float* __restrict__ ln2b,
    const float* __restrict__ lin2w,const float* __restrict__ lin2b,
    const float* __restrict__ ln3g, const float* __restrict__ ln3b,
    const float* __restrict__ lin3w,const float* __restrict__ lin3b,
    float* __restrict__ pf) {
    __shared__ float W1[1024], W2[1024], W3[512], ysh[32];
    const int t = blockIdx.x;          // bias-table row 0..168
    const int lane = threadIdx.x;      // 0..63 (both halves redundant, benign)
    const int j = lane & 31;
    for (int i = lane; i < 1024; i += 64) { W1[i] = lin1w[i]; W2[i] = lin2w[i]; }
    for (int i = lane; i < 512; i += 64)  W3[i] = lin3w[i];
    __syncthreads();

    float b0 = (float)(t / 13) - 6.0f;
    float b1 = (float)(t % 13) - 6.0f;
    float h = b0 * ppw[j] + b1 * ppw[32 + j] + ppb[j];

    // layer 1
    float y = ln_relu_lane(h, ln1g[j], ln1b[j]);
    ysh[j] = y; __syncthreads();
    h = lin1b[j];
#pragma unroll
    for (int k = 0; k < 32; ++k) h += ysh[k] * W1[k * 32 + j];
    __syncthreads();
    // layer 2
    y = ln_relu_lane(h, ln2g[j], ln2b[j]);
    ysh[j] = y; __syncthreads();
    h = lin2b[j];
#pragma unroll
    for (int k = 0; k < 32; ++k) h += ysh[k] * W2[k * 32 + j];
    __syncthreads();
    // layer 3 (32 -> 16)
    y = ln_relu_lane(h, ln3g[j], ln3b[j]);
    ysh[j] = y; __syncthreads();
    if (lane < 16) {
        float a = lin3b[lane];
#pragma unroll
        for (int k = 0; k < 32; ++k) a += ysh[k] * W3[k * 16 + lane];
        pf[t * 16 + lane] = a;
    }
}

// ---------------------------------------------------------------------------
// gather pf[169][16] -> rpb[16][49][49]
// ---------------------------------------------------------------------------
__global__ __launch_bounds__(256) void k_pos_gather(const float* __restrict__ pf,
                                                    float* __restrict__ rpb) {
    int i = blockIdx.x * 256 + threadIdx.x;
    if (i < 16 * 49 * 49) {
        int hh = i / 2401, rem = i % 2401, r = rem / 49, c = rem % 49;
        int ri = (r / 7 - c / 7 + 6) * 13 + (r % 7 - c % 7 + 6);
        rpb[i] = pf[ri * 16 + hh];
    }
}

// ---------------------------------------------------------------------------
// m97-style GEMM: C[M][NT*128] = A[M][512] * B^T   (B stored [col][k])
//  128x128 tile, BK=64, 4 waves (2x2 of 64x64), global_load_lds width 16.
//  grid = (M/128)*NT, must be divisible by 8 (XCD swizzle).
// ---------------------------------------------------------------------------
template<int NT, int ASTR, bool OUTF32>
__global__ __launch_bounds__(256) void k_gemm(const short* __restrict__ A,
                                              const short* __restrict__ Bw,
                                              const float* __restrict__ bias,
                                              short* __restrict__ Cbf,
                                              float* __restrict__ Cf) {
    __shared__ short As[128 * 64];
    __shared__ short Bs[128 * 64];
    const int cpx = gridDim.x >> 3;
    int wg = (blockIdx.x & 7) * cpx + (blockIdx.x >> 3);  // XCD-contiguous
    const int mt = wg / NT, nt = wg % NT;
    const int brow = mt * 128, bcol = nt * 128;
    const int tid = threadIdx.x, w = tid >> 6, lane = tid & 63;
    const int l15 = lane & 15, lhi = lane >> 4;
    const int wr = w >> 1, wc = w & 1;

    const short* Ap = A + (size_t)(brow + (tid >> 3)) * ASTR + (tid & 7) * 8;
    const short* Bp = Bw + (size_t)(bcol + (tid >> 3)) * 512 + (tid & 7) * 8;
    short* asd = As + w * 512;
    short* bsd = Bs + w * 512;

    f32x4 acc[4][4];
#pragma unroll
    for (int m = 0; m < 4; m++)
#pragma unroll
        for (int n = 0; n < 4; n++) acc[m][n] = (f32x4){0.f, 0.f, 0.f, 0.f};

    for (int kt = 0; kt < 8; ++kt) {
        if (kt) __syncthreads();
#pragma unroll
        for (int p = 0; p < 4; ++p) {
            gload_lds16(Ap + (size_t)kt * 64 + (size_t)p * 32 * ASTR, asd + p * 2048);
            gload_lds16(Bp + (size_t)kt * 64 + (size_t)p * 32 * 512,  bsd + p * 2048);
        }
        __syncthreads();
#pragma unroll
        for (int ks = 0; ks < 2; ++ks) {
            bf16x8 af[4], bf[4];
#pragma unroll
            for (int m = 0; m < 4; ++m)
                af[m] = *reinterpret_cast<const bf16x8*>(As + (wr * 64 + m * 16 + l15) * 64 + ks * 32 + lhi * 8);
#pragma unroll
            for (int n = 0; n < 4; ++n)
                bf[n] = *reinterpret_cast<const bf16x8*>(Bs + (wc * 64 + n * 16 + l15) * 64 + ks * 32 + lhi * 8);
#pragma unroll
            for (int m = 0; m < 4; ++m)
#pragma unroll
                for (int n = 0; n < 4; ++n)
                    acc[m][n] = __builtin_amdgcn_mfma_f32_16x16x32_bf16(af[m], bf[n], acc[m][n], 0, 0, 0);
        }
    }
#pragma unroll
    for (int n = 0; n < 4; ++n) {
        int col = bcol + wc * 64 + n * 16 + l15;
        if constexpr (OUTF32) {
            float pb = bias[col];
#pragma unroll
            for (int m = 0; m < 4; ++m)
#pragma unroll
                for (int i = 0; i < 4; ++i) {
                    int row = brow + wr * 64 + m * 16 + lhi * 4 + i;
                    Cf[(size_t)row * (NT * 128) + col] = acc[m][n][i] + pb;
                }
        } else {
#pragma unroll
            for (int m = 0; m < 4; ++m)
#pragma unroll
                for (int i = 0; i < 4; ++i) {
                    int row = brow + wr * 64 + m * 16 + lhi * 4 + i;
                    Cbf[(size_t)row * (NT * 128) + col] = f2bs(acc[m][n][i]);
                }
        }
    }
}

// ---------------------------------------------------------------------------
// Attention: grid = NWIN_CHUNK*4 blocks; 4 waves/block; 1 head per wave.
// q,k frags global->reg; V transposed into per-wave swizzled LDS; P via
// per-wave swizzled LDS.  O overwrites the q-region (cols head*32..+31).
// No __syncthreads needed (all LDS per-wave private).
// ---------------------------------------------------------------------------
__global__ __launch_bounds__(256) void k_attn(short* __restrict__ qkv,
                                              const float* __restrict__ rpbt) {
    __shared__ short Pl[4][4096];   // per-wave 64x64 bf16, byte ^= (r&7)<<4
    __shared__ short Vt[4][2048];   // per-wave 32x64 bf16 (vT), byte ^= (d&7)<<4
    const int bid = blockIdx.x;
    const int wid = (bid & 7) * 128 + (bid >> 3);   // XCD-contiguous (grid 1024)
    const int cw = wid >> 2, qg = wid & 3;
    const int tid = threadIdx.x, w = tid >> 6, lane = tid & 63;
    const int l15 = lane & 15, lhi = lane >> 4;
    const int head = qg * 4 + w;
    char* Pw  = reinterpret_cast<char*>(Pl[w]);
    char* vtw = reinterpret_cast<char*>(Vt[w]);

    // zero vT pad columns (c=49..63)
    for (int t = lane; t < 480; t += 64) {
        int c = 49 + (t >> 5), d = t & 31;
        *reinterpret_cast<short*>(vtw + d * 128 + ((c * 2) ^ ((d & 7) << 4))) = 0;
    }
    short* qb = qkv + (size_t)cw * 49 * 1536 + head * 32;
    const float scale = 0.17677669529663687f;   // 32^-0.5

    // K fragments (B-operand of QK^T): lane group l15 = key row c
    bf16x8 kf[4];
#pragma unroll
    for (int n = 0; n < 4; ++n) {
        int c = n * 16 + l15; if (c > 48) c = 48;
        kf[n] = *reinterpret_cast<const bf16x8*>(qb + 512 + (size_t)c * 1536 + lhi * 8);
    }
    // stage V transposed into LDS
    if (lane < 49) {
        const short* vrow = qb + 1024 + (size_t)lane * 1536;
#pragma unroll
        for (int dv = 0; dv < 4; ++dv) {
            short8_t vv = *reinterpret_cast<const short8_t*>(vrow + dv * 8);
#pragma unroll
            for (int e = 0; e < 8; ++e) {
                int d = dv * 8 + e;
                *reinterpret_cast<short*>(vtw + d * 128 + ((lane * 2) ^ ((d & 7) << 4))) = vv[e];
            }
        }
    }
    // QK^T + softmax + P write
#pragma unroll
    for (int m = 0; m < 4; ++m) {
        int r = m * 16 + l15; if (r > 48) r = 48;
        bf16x8 qf = *reinterpret_cast<const bf16x8*>(qb + (size_t)r * 1536 + lhi * 8);
        f32x4 sc[4];
#pragma unroll
        for (int n = 0; n < 4; ++n) {
            f32x4 z = (f32x4){0.f, 0.f, 0.f, 0.f};
            sc[n] = __builtin_amdgcn_mfma_f32_16x16x32_bf16(qf, kf[n], z, 0, 0, 0);
        }
#pragma unroll
        for (int i = 0; i < 4; ++i) {
            int rr = m * 16 + lhi * 4 + i;
            int rc = rr > 48 ? 48 : rr;
            const float* rp = rpbt + head * 2401 + rc * 49;
            float vv[4];
#pragma unroll
            for (int n = 0; n < 4; ++n) {
                int c = n * 16 + l15;
                vv[n] = (c < 49) ? sc[n][i] * scale + rp[c] : -3.0e38f;
            }
            float mx = fmaxf(fmaxf(vv[0], vv[1]), fmaxf(vv[2], vv[3]));
#pragma unroll
            for (int d = 1; d < 16; d <<= 1) mx = fmaxf(mx, __shfl_xor(mx, d, 64));
            float s0 = 0.f;
#pragma unroll
            for (int n = 0; n < 4; ++n) { vv[n] = __expf(vv[n] - mx); s0 += vv[n]; }
#pragma unroll
            for (int d = 1; d < 16; d <<= 1) s0 += __shfl_xor(s0, d, 64);
            float rs = 1.0f / s0;
#pragma unroll
            for (int n = 0; n < 4; ++n) {
                int c = n * 16 + l15;
                *reinterpret_cast<short*>(Pw + rr * 128 + ((c * 2) ^ ((rr & 7) << 4))) = f2bs(vv[n] * rs);
            }
        }
    }
    // PV
    f32x4 ov[4][2];
#pragma unroll
    for (int m = 0; m < 4; ++m)
#pragma unroll
        for (int n = 0; n < 2; ++n) ov[m][n] = (f32x4){0.f, 0.f, 0.f, 0.f};
#pragma unroll
    for (int ks = 0; ks < 2; ++ks) {
        int cb = ks * 64 + lhi * 16;
        bf16x8 pa[4], vb[2];
#pragma unroll
        for (int m = 0; m < 4; ++m) {
            int r = m * 16 + l15;
            pa[m] = *reinterpret_cast<const bf16x8*>(Pw + r * 128 + (cb ^ ((r & 7) << 4)));
        }
#pragma unroll
        for (int n = 0; n < 2; ++n) {
            int d = n * 16 + l15;
            vb[n] = *reinterpret_cast<const bf16x8*>(vtw + d * 128 + (cb ^ ((d & 7) << 4)));
        }
#pragma unroll
        for (int m = 0; m < 4; ++m)
#pragma unroll
            for (int n = 0; n < 2; ++n)
                ov[m][n] = __builtin_amdgcn_mfma_f32_16x16x32_bf16(pa[m], vb[n], ov[m][n], 0, 0, 0);
    }
    // write O into the (fully consumed) q-region of this head
#pragma unroll
    for (int m = 0; m < 4; ++m)
#pragma unroll
        for (int n = 0; n < 2; ++n)
#pragma unroll
            for (int i = 0; i < 4; ++i) {
                int rr = m * 16 + lhi * 4 + i;
                if (rr < 49) qb[(size_t)rr * 1536 + n * 16 + l15] = f2bs(ov[m][n][i]);
            }
}

// ---------------------------------------------------------------------------
extern "C" void kernel_launch(void* const* d_in, const int* in_sizes, int n_in,
                              void* d_out, int out_size, void* d_ws, size_t ws_size,
                              hipStream_t stream) {
    const float* x    = (const float*)d_in[0];
    const float* qw   = (const float*)d_in[1];
    const float* kvw  = (const float*)d_in[2];
    const float* pw   = (const float*)d_in[3];
    const float* pb   = (const float*)d_in[4];
    const float* ppw  = (const float*)d_in[5];
    const float* ppb  = (const float*)d_in[6];
    const float* ln1g = (const float*)d_in[7];
    const float* ln1b = (const float*)d_in[8];
    const float* lin1w= (const float*)d_in[9];
    const float* lin1b= (const float*)d_in[10];
    const float* ln2g = (const float*)d_in[11];
    const float* ln2b = (const float*)d_in[12];
    const float* lin2w= (const float*)d_in[13];
    const float* lin2b= (const float*)d_in[14];
    const float* ln3g = (const float*)d_in[15];
    const float* ln3b = (const float*)d_in[16];
    const float* lin3w= (const float*)d_in[17];
    const float* lin3b= (const float*)d_in[18];
    float* out = (float*)d_out;

    // workspace layout — total 53,633,024 B (== round-1 proven footprint)
    char* ws = (char*)d_ws;
    short* wqkvT  = (short*)(ws);                  //  1,572,864 B
    short* wprojT = (short*)(ws + 1572864);        //    524,288 B
    float* rpb    = (float*)(ws + 2097152);        //    153,664 B (+pad)
    short* xbc    = (short*)(ws + 2252800);        // 12,845,056 B (chunk)
    short* qkvc   = (short*)(ws + 15097856);       // 38,535,168 B (chunk)
    float* pf     = (float*)(ws + 2252800);        // 10,816 B, aliases xbc head
                                                   // (consumed by k_pos_gather
                                                   //  before first k_prep_x)

    k_prep_w<<<4096, 256, 0, stream>>>(qw, kvw, pw, wqkvT, wprojT);
    k_pos_mlp<<<169, 64, 0, stream>>>(ppw, ppb, ln1g, ln1b, lin1w, lin1b,
                                      ln2g, ln2b, lin2w, lin2b,
                                      ln3g, ln3b, lin3w, lin3b, pf);
    k_pos_gather<<<151, 256, 0, stream>>>(pf, rpb);
    for (int c = 0; c < 4; ++c) {
        const float* xc = x + (size_t)c * MCH * 512;
        float* outc = out + (size_t)c * MCH * 512;
        k_prep_x<<<3136, 256, 0, stream>>>(xc, xbc);
        k_gemm<12, 512, false><<<1176, 256, 0, stream>>>(xbc, wqkvT, nullptr, qkvc, nullptr);
        k_attn<<<1024, 256, 0, stream>>>(qkvc, rpb);
        k_gemm<4, 1536, true><<<392, 256, 0, stream>>>(qkvc, wprojT, pb, nullptr, outc);
    }
}